// Round 6
// baseline (173.692 us; speedup 1.0000x reference)
//
#include <hip/hip_runtime.h>
#include <math.h>

#define IN_DIM 1024
#define OUT_DIM 1024
#define NROWS 8192
#define XSTRIDE 1025   // x rows: 1024 feats + 1 phase

typedef __attribute__((ext_vector_type(8))) short bf16x8;
typedef __attribute__((ext_vector_type(16))) float f32x16;

static __device__ __forceinline__ unsigned f2bf(float f) {
  union { float f; unsigned u; } v; v.f = f;
  unsigned u = v.u;
  return (u + 0x7fffu + ((u >> 16) & 1u)) >> 16;  // RTNE
}

// ---- prep:
//  blocks [0,2048):    W(4,1024,1024) f32 -> Wall bf16, row g=(o&15)|(k<<4)|((o>>4)<<6)
//  blocks [2048,10240): feats -> F bf16 (8192x1024); thread 0 also writes coef[b] (float4)
__global__ __launch_bounds__(256) void prep_kernel(
    const float* __restrict__ x, const float* __restrict__ W,
    unsigned short* __restrict__ Wb, unsigned short* __restrict__ F,
    float* __restrict__ coef)
{
  const int blk = blockIdx.x;
  if (blk < 2048) {
    const int t = blk * 256 + threadIdx.x;
    const int flat = t * 8;                    // 8 elems of W
    const int k = flat >> 20;
    const int o = (flat >> 10) & 1023;
    const int i = flat & 1023;                 // multiple of 8
    const float4 fa = *reinterpret_cast<const float4*>(W + flat);
    const float4 fb = *reinterpret_cast<const float4*>(W + flat + 4);
    uint4 pk;
    pk.x = f2bf(fa.x) | (f2bf(fa.y) << 16);
    pk.y = f2bf(fa.z) | (f2bf(fa.w) << 16);
    pk.z = f2bf(fb.x) | (f2bf(fb.y) << 16);
    pk.w = f2bf(fb.z) | (f2bf(fb.w) << 16);
    const int g = (o & 15) | (k << 4) | ((o >> 4) << 6);
    *reinterpret_cast<uint4*>(Wb + (size_t)g * 1024 + i) = pk;
  } else {
    const int b = blk - 2048;
    const float* xr = x + (size_t)b * XSTRIDE;
    const int i = threadIdx.x * 4;
    ushort4 vv;
    vv.x = (unsigned short)f2bf(xr[i]);     vv.y = (unsigned short)f2bf(xr[i + 1]);
    vv.z = (unsigned short)f2bf(xr[i + 2]); vv.w = (unsigned short)f2bf(xr[i + 3]);
    *reinterpret_cast<ushort4*>(F + (size_t)b * 1024 + i) = vv;
    if (threadIdx.x == 0) {
      const float ps = 4.0f * xr[IN_DIM];
      const int ip = (int)ps;            // trunc, ps in [0,4)
      const int i1 = ip & 3;
      const float mu = ps - (float)ip;
      const float mu2 = mu * mu, mu3 = mu2 * mu;
      const float c0 = -0.5f * mu3 +        mu2 - 0.5f * mu;
      const float c1 =  1.5f * mu3 - 2.5f * mu2 + 1.0f;
      const float c2 = -1.5f * mu3 + 2.0f * mu2 + 0.5f * mu;
      const float c3 =  0.5f * mu3 - 0.5f * mu2;
      const int d0 = (0-i1)&3, d1 = (1-i1)&3, d2 = (2-i1)&3, d3 = (3-i1)&3;
      float4 cv;
      cv.x = d0==0 ? c1 : d0==1 ? c2 : d0==2 ? c3 : c0;
      cv.y = d1==0 ? c1 : d1==1 ? c2 : d1==2 ? c3 : c0;
      cv.z = d2==0 ? c1 : d2==1 ? c2 : d2==2 ? c3 : c0;
      cv.w = d3==0 ? c1 : d3==1 ? c2 : d3==2 ? c3 : c0;
      *reinterpret_cast<float4*>(coef + (size_t)b * 4) = cv;
    }
  }
}

// ---- GEMM: C'(8192 x 4096) = F . Wall^T with 32x32x16 MFMA.
// Knot-in-N layout: within a 32-col fragment col=lane&31 -> o_low=lane&15,
// knot=2*ni+((lane>>4)&1). Lanes l and l^16 hold same rows/o, complementary
// knot pairs -> shfl_xor(16) in the epilogue completes the cubic combine.
#define BM 128
#define BN 128
#define BK 64

__global__ __launch_bounds__(256, 4) void gemm_kernel(
    const unsigned short* __restrict__ F,    // 8192x1024 bf16
    const unsigned short* __restrict__ Wb,   // 4096x1024 bf16, g-layout
    const float* __restrict__ coef,          // 8192x4 f32
    const float* __restrict__ bias,          // 4x1024 f32
    float* __restrict__ out)
{
  __shared__ unsigned short As[BM * BK];   // 16 KB
  __shared__ unsigned short Bs[BN * BK];   // 16 KB

  const int tid  = threadIdx.x;
  const int wave = tid >> 6;
  const int lane = tid & 63;
  const int row0  = blockIdx.y * BM;
  const int col0g = blockIdx.x * BN;

  // staging: thread t -> LDS slot t*16B; XOR chunk swizzle on global source
  const int srow = tid >> 3;
  const int scc  = tid & 7;
  const int sgc  = (scc ^ (srow & 7)) * 8;

  const int wr  = (wave >> 1) * 64;
  const int wc  = (wave & 1) * 64;
  const int l31 = lane & 31;           // fragment row/col index
  const int lh  = lane >> 5;           // k-octet selector
  const int l4  = (lane >> 4) & 1;     // knot-pair bit

  f32x16 acc[2][2];    // [mi][ni], knot = 2*ni + l4 (partner l^16 has 2*ni+1-l4)
  #pragma unroll
  for (int a = 0; a < 2; a++)
    #pragma unroll
    for (int b = 0; b < 2; b++)
      #pragma unroll
      for (int r = 0; r < 16; r++)
        acc[a][b][r] = 0.f;

  const unsigned short* Abase = F  + (size_t)row0  * 1024;
  const unsigned short* Bbase = Wb + (size_t)col0g * 1024;

  for (int kb = 0; kb < 1024; kb += BK) {
    #pragma unroll
    for (int it = 0; it < 4; it++) {
      const int r = srow + it * 32;   // (r&7)==(srow&7): swizzle invariant
      __builtin_amdgcn_global_load_lds(
          (const __attribute__((address_space(1))) void*)(Abase + (size_t)r * 1024 + kb + sgc),
          (__attribute__((address_space(3))) void*)(As + r * BK + scc * 8), 16, 0, 0);
      __builtin_amdgcn_global_load_lds(
          (const __attribute__((address_space(1))) void*)(Bbase + (size_t)r * 1024 + kb + sgc),
          (__attribute__((address_space(3))) void*)(Bs + r * BK + scc * 8), 16, 0, 0);
    }
    __syncthreads();

    #pragma unroll
    for (int kk = 0; kk < BK; kk += 16) {
      const int lc = ((kk >> 3) + lh);   // chunk pair base for this k-step
      bf16x8 af[2], bfr[2];
      #pragma unroll
      for (int mi = 0; mi < 2; mi++) {
        const int r = wr + mi * 32 + l31;
        af[mi] = *reinterpret_cast<const bf16x8*>(As + r * BK + (lc ^ (r & 7)) * 8);
      }
      #pragma unroll
      for (int ni = 0; ni < 2; ni++) {
        const int r = wc + ni * 32 + l31;
        bfr[ni] = *reinterpret_cast<const bf16x8*>(Bs + r * BK + (lc ^ (r & 7)) * 8);
      }
      #pragma unroll
      for (int mi = 0; mi < 2; mi++)
        #pragma unroll
        for (int ni = 0; ni < 2; ni++)
          acc[mi][ni] = __builtin_amdgcn_mfma_f32_32x32x16_bf16(
              af[mi], bfr[ni], acc[mi][ni], 0, 0, 0);
    }
    __syncthreads();
  }

  // ---- epilogue: gather 4 knots (2 own + 2 via shfl_xor 16), cubic+bias+elu
  const int o = (lane & 15) + 16 * (2 * blockIdx.x + (wave & 1));
  const float b0 = bias[o];
  const float b1 = bias[OUT_DIM + o];
  const float b2 = bias[2 * OUT_DIM + o];
  const float b3 = bias[3 * OUT_DIM + o];
  #pragma unroll
  for (int mi = 0; mi < 2; mi++) {
    #pragma unroll
    for (int reg = 0; reg < 16; reg++) {
      const int rloc = wr + mi * 32 + (reg & 3) + 8 * (reg >> 2) + 4 * lh;
      const float own0 = acc[mi][0][reg];            // knot l4
      const float own1 = acc[mi][1][reg];            // knot 2+l4
      const float par0 = __shfl_xor(own0, 16, 64);   // knot 1-l4
      const float par1 = __shfl_xor(own1, 16, 64);   // knot 3-l4
      const float k0 = l4 ? par0 : own0;
      const float k1 = l4 ? own0 : par0;
      const float k2 = l4 ? par1 : own1;
      const float k3 = l4 ? own1 : par1;
      const float4 c = *reinterpret_cast<const float4*>(coef + (size_t)(row0 + rloc) * 4);
      float v = c.x * (k0 + b0) + c.y * (k1 + b1)
              + c.z * (k2 + b2) + c.w * (k3 + b3);
      const float e = __expf(v) - 1.0f;              // elu via hw v_exp_f32
      v = (v > 0.0f) ? v : e;
      out[(size_t)(row0 + rloc) * OUT_DIM + o] = v;
    }
  }
}

extern "C" void kernel_launch(void* const* d_in, const int* in_sizes, int n_in,
                              void* d_out, int out_size, void* d_ws, size_t ws_size,
                              hipStream_t stream) {
  const float* x  = (const float*)d_in[0];   // (8192, 1025)
  const float* wk = (const float*)d_in[1];   // (4, 1024, 1024)
  const float* bk = (const float*)d_in[2];   // (4, 1024)
  float* out = (float*)d_out;                // (8192, 1024) fp32

  char* ws = (char*)d_ws;
  unsigned short* Wb = (unsigned short*)ws;                   // 8 MB
  unsigned short* F  = (unsigned short*)(ws + (8u << 20));    // 16 MB
  float* coef        = (float*)(ws + (24u << 20));            // 128 KB

  hipLaunchKernelGGL(prep_kernel, dim3(2048 + NROWS), dim3(256), 0, stream,
                     x, wk, Wb, F, coef);
  hipLaunchKernelGGL(gemm_kernel, dim3(4096 / BN, NROWS / BM), dim3(256), 0, stream,
                     F, Wb, coef, bk, out);
}

// Round 8
// 161.311 us; speedup vs baseline: 1.0768x; 1.0768x over previous
//
#include <hip/hip_runtime.h>
#include <math.h>

#define IN_DIM 1024
#define OUT_DIM 1024
#define NROWS 8192
#define XSTRIDE 1025   // x rows: 1024 feats + 1 phase

typedef __attribute__((ext_vector_type(8))) short bf16x8;
typedef __attribute__((ext_vector_type(4))) float f32x4;

static __device__ __forceinline__ unsigned f2bf(float f) {
  union { float f; unsigned u; } v; v.f = f;
  unsigned u = v.u;
  return (u + 0x7fffu + ((u >> 16) & 1u)) >> 16;  // RTNE
}

// ---- prep:
//  blocks [0,2048):    W(4,1024,1024) f32 -> Wall bf16, row g=(o&15)|(k<<4)|((o>>4)<<6)
//  blocks [2048,6144): feats -> F bf16, 2 rows/block, 16B stores;
//                      threads 0 & 128 write coef[row] (float4)
__global__ __launch_bounds__(256) void prep_kernel(
    const float* __restrict__ x, const float* __restrict__ W,
    unsigned short* __restrict__ Wb, unsigned short* __restrict__ F,
    float* __restrict__ coef)
{
  const int blk = blockIdx.x;
  if (blk < 2048) {
    const int t = blk * 256 + threadIdx.x;
    const int flat = t * 8;                    // 8 elems of W
    const int k = flat >> 20;
    const int o = (flat >> 10) & 1023;
    const int i = flat & 1023;                 // multiple of 8
    const float4 fa = *reinterpret_cast<const float4*>(W + flat);
    const float4 fb = *reinterpret_cast<const float4*>(W + flat + 4);
    uint4 pk;
    pk.x = f2bf(fa.x) | (f2bf(fa.y) << 16);
    pk.y = f2bf(fa.z) | (f2bf(fa.w) << 16);
    pk.z = f2bf(fb.x) | (f2bf(fb.y) << 16);
    pk.w = f2bf(fb.z) | (f2bf(fb.w) << 16);
    const int g = (o & 15) | (k << 4) | ((o >> 4) << 6);
    *reinterpret_cast<uint4*>(Wb + (size_t)g * 1024 + i) = pk;
  } else {
    // 2 rows per block: thread t -> row (t>>7), cols (t&127)*8 .. +7
    const int b = (blk - 2048) * 2 + (threadIdx.x >> 7);
    const float* xr = x + (size_t)b * XSTRIDE;
    const int i = (threadIdx.x & 127) * 8;
    uint4 pk;
    pk.x = f2bf(xr[i])     | (f2bf(xr[i + 1]) << 16);
    pk.y = f2bf(xr[i + 2]) | (f2bf(xr[i + 3]) << 16);
    pk.z = f2bf(xr[i + 4]) | (f2bf(xr[i + 5]) << 16);
    pk.w = f2bf(xr[i + 6]) | (f2bf(xr[i + 7]) << 16);
    *reinterpret_cast<uint4*>(F + (size_t)b * 1024 + i) = pk;
    if ((threadIdx.x & 127) == 0) {
      const float ps = 4.0f * xr[IN_DIM];
      const int ip = (int)ps;            // trunc, ps in [0,4)
      const int i1 = ip & 3;
      const float mu = ps - (float)ip;
      const float mu2 = mu * mu, mu3 = mu2 * mu;
      const float c0 = -0.5f * mu3 +        mu2 - 0.5f * mu;
      const float c1 =  1.5f * mu3 - 2.5f * mu2 + 1.0f;
      const float c2 = -1.5f * mu3 + 2.0f * mu2 + 0.5f * mu;
      const float c3 =  0.5f * mu3 - 0.5f * mu2;
      const int d0 = (0-i1)&3, d1 = (1-i1)&3, d2 = (2-i1)&3, d3 = (3-i1)&3;
      float4 cv;
      cv.x = d0==0 ? c1 : d0==1 ? c2 : d0==2 ? c3 : c0;
      cv.y = d1==0 ? c1 : d1==1 ? c2 : d1==2 ? c3 : c0;
      cv.z = d2==0 ? c1 : d2==1 ? c2 : d2==2 ? c3 : c0;
      cv.w = d3==0 ? c1 : d3==1 ? c2 : d3==2 ? c3 : c0;
      *reinterpret_cast<float4*>(coef + (size_t)b * 4) = cv;
    }
  }
}

// ---- GEMM: C'(8192 x 4096) = F . Wall^T, knots interleaved in N so that
// fragment ni == knot index; cubic combine + bias + elu fused per-lane in
// epilogue. (Identical to the R5 69 µs / ~995 TF kernel — do not touch.)
#define BM 128
#define BN 128   // g-columns = 32 o's x 4 knots
#define BK 64

__global__ __launch_bounds__(256, 4) void gemm_kernel(
    const unsigned short* __restrict__ F,    // 8192x1024 bf16
    const unsigned short* __restrict__ Wb,   // 4096x1024 bf16, g-layout
    const float* __restrict__ coef,          // 8192x4 f32
    const float* __restrict__ bias,          // 4x1024 f32
    float* __restrict__ out)
{
  __shared__ unsigned short As[BM * BK];   // 16 KB
  __shared__ unsigned short Bs[BN * BK];   // 16 KB

  const int tid  = threadIdx.x;
  const int wave = tid >> 6;
  const int lane = tid & 63;
  const int row0  = blockIdx.y * BM;
  const int col0g = blockIdx.x * BN;

  // staging: thread t -> LDS slot t*16B; XOR chunk swizzle on global source
  const int srow = tid >> 3;
  const int scc  = tid & 7;
  const int sgc  = (scc ^ (srow & 7)) * 8;

  const int wr = (wave >> 1) * 64;
  const int wc = (wave & 1) * 64;
  const int fm = lane & 15;
  const int fq = lane >> 4;

  f32x4 acc[4][4];   // [mi][ni=knot]
  const f32x4 zero = {0.f, 0.f, 0.f, 0.f};
  #pragma unroll
  for (int a = 0; a < 4; a++)
    #pragma unroll
    for (int b = 0; b < 4; b++)
      acc[a][b] = zero;

  const unsigned short* Abase = F  + (size_t)row0  * 1024;
  const unsigned short* Bbase = Wb + (size_t)col0g * 1024;

  for (int kb = 0; kb < 1024; kb += BK) {
    #pragma unroll
    for (int it = 0; it < 4; it++) {
      const int r = srow + it * 32;   // (r&7)==(srow&7): swizzle invariant
      __builtin_amdgcn_global_load_lds(
          (const __attribute__((address_space(1))) void*)(Abase + (size_t)r * 1024 + kb + sgc),
          (__attribute__((address_space(3))) void*)(As + r * BK + scc * 8), 16, 0, 0);
      __builtin_amdgcn_global_load_lds(
          (const __attribute__((address_space(1))) void*)(Bbase + (size_t)r * 1024 + kb + sgc),
          (__attribute__((address_space(3))) void*)(Bs + r * BK + scc * 8), 16, 0, 0);
    }
    __syncthreads();

    #pragma unroll
    for (int kk = 0; kk < BK; kk += 32) {
      bf16x8 af[4], bfr[4];
      #pragma unroll
      for (int mi = 0; mi < 4; mi++) {
        const int r  = wr + mi * 16 + fm;
        const int lc = ((kk >> 3) + fq) ^ (fm & 7);
        af[mi] = *reinterpret_cast<const bf16x8*>(As + r * BK + lc * 8);
      }
      #pragma unroll
      for (int ni = 0; ni < 4; ni++) {
        const int r  = wc + ni * 16 + fm;
        const int lc = ((kk >> 3) + fq) ^ (fm & 7);
        bfr[ni] = *reinterpret_cast<const bf16x8*>(Bs + r * BK + lc * 8);
      }
      #pragma unroll
      for (int mi = 0; mi < 4; mi++)
        #pragma unroll
        for (int ni = 0; ni < 4; ni++)
          acc[mi][ni] = __builtin_amdgcn_mfma_f32_16x16x32_bf16(
              af[mi], bfr[ni], acc[mi][ni], 0, 0, 0);
    }
    __syncthreads();
  }

  // ---- epilogue: v = sum_k c_k*(acc_k + bias_k[o]); fast elu; dense store
  const int o = fm + 16 * (2 * blockIdx.x + (wave & 1));
  const float b0 = bias[o];
  const float b1 = bias[OUT_DIM + o];
  const float b2 = bias[2 * OUT_DIM + o];
  const float b3 = bias[3 * OUT_DIM + o];
  #pragma unroll
  for (int mi = 0; mi < 4; mi++) {
    #pragma unroll
    for (int r = 0; r < 4; r++) {
      const int rloc = wr + mi * 16 + (fq << 2) + r;
      const float4 c = *reinterpret_cast<const float4*>(coef + (size_t)(row0 + rloc) * 4);
      float v = c.x * (acc[mi][0][r] + b0)
              + c.y * (acc[mi][1][r] + b1)
              + c.z * (acc[mi][2][r] + b2)
              + c.w * (acc[mi][3][r] + b3);
      const float e = __expf(v) - 1.0f;   // elu via hw v_exp_f32
      v = (v > 0.0f) ? v : e;
      out[(size_t)(row0 + rloc) * OUT_DIM + o] = v;
    }
  }
}

extern "C" void kernel_launch(void* const* d_in, const int* in_sizes, int n_in,
                              void* d_out, int out_size, void* d_ws, size_t ws_size,
                              hipStream_t stream) {
  const float* x  = (const float*)d_in[0];   // (8192, 1025)
  const float* wk = (const float*)d_in[1];   // (4, 1024, 1024)
  const float* bk = (const float*)d_in[2];   // (4, 1024)
  float* out = (float*)d_out;                // (8192, 1024) fp32

  char* ws = (char*)d_ws;
  unsigned short* Wb = (unsigned short*)ws;                   // 8 MB
  unsigned short* F  = (unsigned short*)(ws + (8u << 20));    // 16 MB
  float* coef        = (float*)(ws + (24u << 20));            // 128 KB

  hipLaunchKernelGGL(prep_kernel, dim3(2048 + NROWS / 2), dim3(256), 0, stream,
                     x, wk, Wb, F, coef);
  hipLaunchKernelGGL(gemm_kernel, dim3(4096 / BN, NROWS / BM), dim3(256), 0, stream,
                     F, Wb, coef, bk, out);
}